// Round 4
// baseline (134.477 us; speedup 1.0000x reference)
//
#include <hip/hip_runtime.h>

// QuantizedBKCore: tridiagonal resolvent diagonal via two continued-fraction
// sweeps, bit-exact vs numpy float32/complex64 reference (validated R1-R15:
// absmax == 0).
//
// R16 = R15 restructured for ILP (latency-bound fix). Evidence R12-R15:
// VALUBusy x dur ~ const (~30k VALU-us) => time = VALU_cycles/VALUBusy;
// occupancy is stuck at 4 waves/SIMD (launch_bounds(,8) soft-failed) and
// R13 showed more waves just dilutes per-wave issue. The stall is dependent-
// chain latency: npdiv is a ~90-cycle critical path with ~60 issue cycles,
// and the old backward main was a SINGLE serial chain (1-wide), forward
// main 2-wide. R16 splits each lane's 16-element segment into two halves
// and runs two counter-directional chains at once:
//   phase 1 (2-wide): backward fills R[15..8] || forward fills L[0..7]
//   phase 2 (4-wide): backward continues 7..0 combining on-the-fly with
//     stored L || forward continues 8..15 combining with stored R
//     (combine npdivs are independent of the carry chains)
// Same 46 npdivs, same 32 array VGPRs (L-half/R-half recycled in place as
// G), every output's dataflow graph op-identical to R12-R15 => absmax 0 by
// construction. Burst 128-B line store kept (WRITE_SIZE stays 64 MiB).

#define SEG    16                 // elements per lane
#define HSEG   (SEG/2)            // half-segment
#define WCHEAP 16                 // approximate warmup steps (rcp-based)
#define WEXACT 8                  // exact Smith-tail steps
#define WARM   (WCHEAP + WEXACT)  // 24 total; HALO multiple of 4
#define LANES  64                 // lanes per wave
#define WAVES  4                  // waves (chunks) per block
#define NTHR   (LANES * WAVES)    // 256 threads per block
#define CHUNK  (LANES*SEG)        // 1024 elements per wave-chunk
#define BCHUNK (WAVES * CHUNK)    // 4096 elements per block
#define HALO   WARM
#define BSTAGE (BCHUNK + 2*HALO)  // 4144 staged negA values (shared halos)
#define SPAD   (BSTAGE + BSTAGE/32 + 1)  // stride-33 padding (2-way only: free)

struct C2 { float r, i; };

__device__ __forceinline__ int padi(int i) { return i + (i >> 5); }

// IEEE-correctly-rounded f32 divide for mid-range normal operands.
// Exactly the Newton core of LLVM's gfx9 fdiv expansion; div_scale/div_fixup
// are identity for den in [~0.7, 26], num <= 130 (all values arising here),
// so the result is bit-identical to the compiler's a/b (= numpy's divide).
__device__ __forceinline__ float fdiv_ieee(float num, float den) {
  const float r0 = __builtin_amdgcn_rcpf(den);
  const float e0 = __builtin_fmaf(-den, r0, 1.0f);
  const float r1 = __builtin_fmaf(e0, r0, r0);
  const float q0 = num * r1;
  const float e1 = __builtin_fmaf(-den, q0, num);
  const float q1 = __builtin_fmaf(e1, r1, q0);
  const float e2 = __builtin_fmaf(-den, q1, num);
  return __builtin_fmaf(e2, r1, q1);
}

// numpy CFLOAT_divide (Smith), numerator (nr, 0), no FMA contraction in the
// surrounding mul/add ops (explicit fmaf inside fdiv_ieee is intentional).
__device__ __forceinline__ C2 npdiv(float nr, float dr, float di) {
  #pragma clang fp contract(off)
  const bool  b   = fabsf(dr) >= fabsf(di);
  const float num = b ? di : dr;
  const float den = b ? dr : di;
  const float rat = fdiv_ieee(num, den);  // == IEEE num/den (range-proven)
  const float t   = num * rat;
  const float s   = den + t;              // mul + add, NOT fma
  const float scl = fdiv_ieee(1.0f, s);   // == IEEE 1/s
  const float u   = nr * scl;
  const float m   = nr * rat;
  const float w   = m * scl;
  C2 o;
  o.r = b ? u : w;
  o.i = b ? -w : -u;                      // sign-of-product flip is exact
  return o;
}

// exact continued-fraction step: carry <- cv / (z - a - carry), z = i
__device__ __forceinline__ void cf_step(float na, float cv, float& cr, float& ci) {
  #pragma clang fp contract(off)
  const float dr = na - cr;
  const float di = 1.0f - ci;
  const C2 nc = npdiv(cv, dr, di);
  cr = nc.r; ci = nc.i;
}

// cheap approximate step (warmup only, pre-merge): same map via rcp.
// cv=0 halo fakes stay bit-transparent: t=0 -> carry=(+-0,-+0).
__device__ __forceinline__ void cf_cheap(float na, float cv, float& cr, float& ci) {
  const float dr = na - cr;
  const float di = 1.0f - ci;
  const float m2 = dr * dr + di * di;         // in [1, ~130]
  const float r  = __builtin_amdgcn_rcpf(m2); // v_rcp_f32, ~1 ulp
  const float t  = cv * r;
  cr = dr * t;
  ci = -(di * t);
}

// -(clip(h0_diag + fake_quantize(v), -10, 10)); exact op order.
__device__ __forceinline__ float neg_a(float vv, float hd) {
  #pragma clang fp contract(off)
  float q = rintf(vv);                  // round half-even == np.rint
  q = fminf(fmaxf(q, -128.0f), 127.0f);
  float he = hd + q;
  he = fminf(fmaxf(he, -10.0f), 10.0f);
  return 0.0f - he;                     // Re(z - a)
}

// clip(+-100) -> rint -> clip(+-128); exact ops.
__device__ __forceinline__ float fq_out(float x) {
  #pragma clang fp contract(off)
  x = fminf(fmaxf(x, -100.0f), 100.0f);
  x = rintf(x);
  x = fminf(fmaxf(x, -128.0f), 127.0f);
  return x;
}

// ccf[i] = cc[i-HALO] zero-padded: i in [0, N + 2*HALO + 8)
__global__ void cc_kernel(const float* __restrict__ hsub,
                          const float* __restrict__ hsup,
                          float* __restrict__ ccf, int N) {
  #pragma clang fp contract(off)
  const int i = blockIdx.x * blockDim.x + threadIdx.x;
  if (i < N + 2*HALO + 8) {
    const int k = i - HALO;
    ccf[i] = (k >= 0 && k < N - 1) ? hsub[k] * hsup[k] : 0.0f;
  }
}

// w[0..7] = cc[m0..m0+7], where (m0+HALO) % 4 == 0: two aligned float4 loads.
__device__ __forceinline__ void load8_f(const float4* __restrict__ cc4,
                                        int m0, float* w) {
  const int q = (m0 + HALO) >> 2;
  const float4 A = cc4[q];
  const float4 B = cc4[q + 1];
  w[0]=A.x; w[1]=A.y; w[2]=A.z; w[3]=A.w;
  w[4]=B.x; w[5]=B.y; w[6]=B.z; w[7]=B.w;
}

// w[0..7] = cc[m0..m0+7], where (m0+HALO) % 4 == 3: three aligned float4 loads.
__device__ __forceinline__ void load8_b(const float4* __restrict__ cc4,
                                        int m0, float* w) {
  const int q = (m0 + HALO - 3) >> 2;   // (m0+HALO-3) % 4 == 0
  const float4 A = cc4[q];              // covers m0-3 .. m0
  const float4 B = cc4[q + 1];          // m0+1 .. m0+4
  const float4 C = cc4[q + 2];          // m0+5 .. m0+8
  w[0]=A.w;
  w[1]=B.x; w[2]=B.y; w[3]=B.z; w[4]=B.w;
  w[5]=C.x; w[6]=C.y; w[7]=C.z;
}

__global__ void __launch_bounds__(NTHR)
bk_kernel(const float* __restrict__ v,
          const float* __restrict__ hdiag,
          const float* __restrict__ ccf,      // zero-padded couplings (d_ws)
          float2* __restrict__ out,
          int N, int chunks_per_row, int blocks_per_row) {
  #pragma clang fp contract(off)
  __shared__ float sA[SPAD];            // negA for 4 chunks + halos: ~17.1 KB

  const int tid  = threadIdx.x;
  const int lane = tid & (LANES - 1);
  const int wv   = tid >> 6;
  const int row  = blockIdx.x / blocks_per_row;
  const int cb   = blockIdx.x - row * blocks_per_row;
  const int bbase = cb * BCHUNK;        // first element of the block's span
  const long rowoff = (long)row * N;
  const float4* cc4 = (const float4*)ccf;

  // ---- stage negA for all 4 chunks, 256-wide coalesced; zeros outside [0,N)
  for (int i = tid; i < BSTAGE; i += NTHR) {
    const int k = bbase - HALO + i;
    float na = 0.0f;
    if (k >= 0 && k < N) na = neg_a(v[rowoff + k], hdiag[k]);
    sA[padi(i)] = na;
  }
  __syncthreads();

  const int chunk = cb * WAVES + wv;
  if (chunk < chunks_per_row) {
    const int base = bbase + wv * CHUNK;  // this wave's chunk start
    const int s0  = base + lane * SEG;
    const int s1  = s0 + SEG;
    const int loff = bbase - HALO;        // global index of sA[0]
    const int li0 = s0 - loff;            // sA (unpadded) index of s0

    // Ar/Ai: L[0..7] then recycled as G[0..7]; Br/Bi: R[8..15] then G[8..15]
    float Ar[HSEG], Ai[HSEG], Br[HSEG], Bi[HSEG];
    float crB, ciB;                       // backward carry (R)
    float crF, ciF;                       // forward carry (L)
    float wcB[8], wcF[8];

    // ---- paired warmups (independent chains, interleaved for ILP) ---------
    // bwd: R[k-1] = cc[k-1] / (z - a[k] - R[k]), k = s1+23 .. s1, carry 0.
    // fwd: L[k+1] = cc[k]   / (z - a[k] - L[k]), k = s0-24 .. s0-1, carry 0.
    // Groups g=0,1: cheap rcp steps (pre-merge). g=2: exact Smith tail.
    crB = 0.0f; ciB = 0.0f; crF = 0.0f; ciF = 0.0f;
    #pragma unroll
    for (int g = 0; g < WARM / 8; ++g) {
      const int kh = s1 + (WARM - 1) - 8 * g;   // bwd group high k
      const int kl = s0 - WARM + 8 * g;         // fwd group low k
      load8_b(cc4, kh - 8, wcB);                // wcB[j'] = cc[kh-8+j']
      load8_f(cc4, kl, wcF);                    // wcF[j]  = cc[kl+j]
      #pragma unroll
      for (int j = 0; j < 8; ++j) {
        const float naB = sA[padi(kh - j - loff)];
        const float naF = sA[padi(kl + j - loff)];
        if (g < (WCHEAP / 8)) {                 // cheap phase
          cf_cheap(naB, wcB[7 - j], crB, ciB);  // cc[k-1], k = kh-j
          cf_cheap(naF, wcF[j],     crF, ciF);  // cc[k],   k = kl+j
        } else {                                // exact Smith tail
          cf_step(naB, wcB[7 - j], crB, ciB);
          cf_step(naF, wcF[j],     crF, ciF);
        }
      }
    }
    Br[HSEG-1] = crB; Bi[HSEG-1] = ciB;         // R[15]

    // ---- main cc windows: w0 = cc[s0..s0+7], w1 = cc[s0+8..s0+15] ---------
    float w0[8], w1[8];
    load8_f(cc4, s0,     w0);
    load8_f(cc4, s0 + 8, w1);

    // ---- phase 1 (2-wide ILP): bwd fills R[14..8] || fwd fills L[0..7] ----
    // bwd step at element t uses na[t], cc[t-1]; fwd advance at t uses
    // na[t], cc[t]. Same ops as the old single-direction mains.
    #pragma unroll
    for (int k = 0; k < 8; ++k) {
      // fwd: store L[k], advance to L[k+1]
      Ar[k] = crF; Ai[k] = ciF;
      const float naF = sA[padi(li0 + k)];
      const float drL = naF - crF;
      const float diL = 1.0f - ciF;
      { const C2 nc = npdiv(w0[k], drL, diL); crF = nc.r; ciF = nc.i; }
      // bwd: step at t = 15-k producing R[14-k] (7 steps)
      if (k < 7) {
        const float naB = sA[padi(li0 + 15 - k)];
        cf_step(naB, w1[6 - k], crB, ciB);      // cc[s0+14-k]
        Br[6 - k] = crB; Bi[6 - k] = ciB;       // R[14-k]
      }
    }
    // here: crF = L[8], crB = R[8]

    // ---- phase 2 (4-wide ILP): two carry chains + two independent combines
    // delta: t = 8..15 combining with stored R (Br/Bi), advancing L
    // gamma: u = 7..0, bwd step produces R[u] on the fly, combine with
    //        stored L (Ar/Ai). G recycles the array slot it just read.
    #pragma unroll
    for (int k = 0; k < 8; ++k) {
      // delta
      const int t = 8 + k;
      const float naD = sA[padi(li0 + t)];
      const float drLD = naD - crF;
      const float diLD = 1.0f - ciF;
      const float drfD = drLD - Br[k];
      const float difD = diLD - Bi[k];
      const C2 GD = npdiv(1.0f, drfD, difD);
      if (k < 7) {                              // advance L (skip at t=15)
        const C2 nc = npdiv(w1[k], drLD, diLD); // cc[s0+8+k]
        crF = nc.r; ciF = nc.i;
      }
      Br[k] = fq_out(GD.r); Bi[k] = fq_out(GD.i);
      // gamma
      const int u = 7 - k;
      const float naS = sA[padi(li0 + u + 1)];
      cf_step(naS, w0[u], crB, ciB);            // step at elem u+1 -> R[u]
      const float naG = sA[padi(li0 + u)];
      const float drLG = naG - Ar[u];
      const float diLG = 1.0f - Ai[u];
      const float drfG = drLG - crB;
      const float difG = diLG - ciB;
      const C2 GG = npdiv(1.0f, drfG, difG);
      Ar[u] = fq_out(GG.r); Ai[u] = fq_out(GG.i);
    }

    // ---- burst-write the lane's full 128-B line: 8 back-to-back dwordx4 ---
    // (line opened and closed within one issue window -> L2 write-combine
    //  works at any occupancy; &out[rowoff+s0] is 128-B aligned)
    float4* op = (float4*)(&out[rowoff + s0]);
    #pragma unroll
    for (int q = 0; q < 4; ++q) {
      float4 f4;
      f4.x = Ar[2*q];     f4.y = Ai[2*q];
      f4.z = Ar[2*q + 1]; f4.w = Ai[2*q + 1];
      op[q] = f4;
    }
    #pragma unroll
    for (int q = 0; q < 4; ++q) {
      float4 f4;
      f4.x = Br[2*q];     f4.y = Bi[2*q];
      f4.z = Br[2*q + 1]; f4.w = Bi[2*q + 1];
      op[4 + q] = f4;
    }
  }
}

extern "C" void kernel_launch(void* const* d_in, const int* in_sizes, int n_in,
                              void* d_out, int out_size, void* d_ws, size_t ws_size,
                              hipStream_t stream) {
  const float* v    = (const float*)d_in[0];
  const float* hd   = (const float*)d_in[1];
  const float* hsub = (const float*)d_in[2];
  const float* hsup = (const float*)d_in[3];
  const int N = in_sizes[1];
  const int B = in_sizes[0] / N;
  const int chunks = (N + CHUNK - 1) / CHUNK;        // 16 for N=16384 (exact)
  const int bpr    = (chunks + WAVES - 1) / WAVES;   // 4 blocks per row

  float* ccf = (float*)d_ws;                     // N + 2*HALO + 8 floats
  const int ccn = N + 2*HALO + 8;
  cc_kernel<<<(ccn + 255) / 256, 256, 0, stream>>>(hsub, hsup, ccf, N);
  bk_kernel<<<B * bpr, NTHR, 0, stream>>>(v, hd, ccf, (float2*)d_out,
                                          N, chunks, bpr);
}

// Round 5
// 125.965 us; speedup vs baseline: 1.0676x; 1.0676x over previous
//
#include <hip/hip_runtime.h>

// QuantizedBKCore: tridiagonal resolvent diagonal via two continued-fraction
// sweeps, bit-exact vs numpy float32/complex64 reference (validated R1-R16:
// absmax == 0).
//
// R17 = R15 structure + per-8 burst stores + batched LDS reads.
// Evidence R12-R16: total VALU work is invariant (VALUBusy x dur ~ 30k
// VALU-us); time = work/VALUBusy. Occupancy tracks peak live VGPRs:
// R13 (scattered stores, small live set) 81%; R14/R15 (32-reg full-line
// G burst) 50%; R16 (4-stream interleave) 38% + LDS waits threaded into
// the carry chains (VALUBusy 33). The 128-B full-line burst forces 32 G
// values live at once -> crosses the 64-VGPR bin -> 4 waves/SIMD.
// R17 keeps the proven R15 sweep order but:
//   (a) forward main runs as two groups of 8: each group recycles
//       Rr/Ri[t] in place as fq_out(G) (16 live, not 32) and immediately
//       bursts its 64 B as 4x dwordx4. The two half-line bursts of a
//       128-B line are ~0.3-0.5 us apart; dirty-line churn per XCD in
//       that window (~100 KB) << 4 MiB L2, so write-combining holds
//       (unlike R13's whole-phase-open lines).
//   (b) all sA (negA) reads are batched into per-group register arrays
//       (warmup + both mains): 8 ds_reads issue back-to-back BEFORE the
//       chain consumes them, keeping LDS latency off the serial npdiv
//       chains (the R16 lesson, applied without the 4-stream live-set).
// Arithmetic op sequence per output is identical to R12-R16 (cheap rcp
// warmup 16 + exact Smith tail 8, fdiv_ieee Newton core, float4 cc loads)
// => absmax 0 by construction.

#define SEG    16                 // elements per lane
#define WCHEAP 16                 // approximate warmup steps (rcp-based)
#define WEXACT 8                  // exact Smith-tail steps
#define WARM   (WCHEAP + WEXACT)  // 24 total; HALO multiple of 4
#define LANES  64                 // lanes per wave
#define WAVES  4                  // waves (chunks) per block
#define NTHR   (LANES * WAVES)    // 256 threads per block
#define CHUNK  (LANES*SEG)        // 1024 elements per wave-chunk
#define BCHUNK (WAVES * CHUNK)    // 4096 elements per block
#define HALO   WARM
#define BSTAGE (BCHUNK + 2*HALO)  // 4144 staged negA values (shared halos)
#define SPAD   (BSTAGE + BSTAGE/32 + 1)  // stride-33 padding (2-way only: free)

struct C2 { float r, i; };

__device__ __forceinline__ int padi(int i) { return i + (i >> 5); }

// IEEE-correctly-rounded f32 divide for mid-range normal operands.
// Exactly the Newton core of LLVM's gfx9 fdiv expansion; div_scale/div_fixup
// are identity for den in [~0.7, 26], num <= 130 (all values arising here),
// so the result is bit-identical to the compiler's a/b (= numpy's divide).
__device__ __forceinline__ float fdiv_ieee(float num, float den) {
  const float r0 = __builtin_amdgcn_rcpf(den);
  const float e0 = __builtin_fmaf(-den, r0, 1.0f);
  const float r1 = __builtin_fmaf(e0, r0, r0);
  const float q0 = num * r1;
  const float e1 = __builtin_fmaf(-den, q0, num);
  const float q1 = __builtin_fmaf(e1, r1, q0);
  const float e2 = __builtin_fmaf(-den, q1, num);
  return __builtin_fmaf(e2, r1, q1);
}

// numpy CFLOAT_divide (Smith), numerator (nr, 0), no FMA contraction in the
// surrounding mul/add ops (explicit fmaf inside fdiv_ieee is intentional).
__device__ __forceinline__ C2 npdiv(float nr, float dr, float di) {
  #pragma clang fp contract(off)
  const bool  b   = fabsf(dr) >= fabsf(di);
  const float num = b ? di : dr;
  const float den = b ? dr : di;
  const float rat = fdiv_ieee(num, den);  // == IEEE num/den (range-proven)
  const float t   = num * rat;
  const float s   = den + t;              // mul + add, NOT fma
  const float scl = fdiv_ieee(1.0f, s);   // == IEEE 1/s
  const float u   = nr * scl;
  const float m   = nr * rat;
  const float w   = m * scl;
  C2 o;
  o.r = b ? u : w;
  o.i = b ? -w : -u;                      // sign-of-product flip is exact
  return o;
}

// exact continued-fraction step: carry <- cv / (z - a - carry), z = i
__device__ __forceinline__ void cf_step(float na, float cv, float& cr, float& ci) {
  #pragma clang fp contract(off)
  const float dr = na - cr;
  const float di = 1.0f - ci;
  const C2 nc = npdiv(cv, dr, di);
  cr = nc.r; ci = nc.i;
}

// cheap approximate step (warmup only, pre-merge): same map via rcp.
// cv=0 halo fakes stay bit-transparent: t=0 -> carry=(+-0,-+0).
__device__ __forceinline__ void cf_cheap(float na, float cv, float& cr, float& ci) {
  const float dr = na - cr;
  const float di = 1.0f - ci;
  const float m2 = dr * dr + di * di;         // in [1, ~130]
  const float r  = __builtin_amdgcn_rcpf(m2); // v_rcp_f32, ~1 ulp
  const float t  = cv * r;
  cr = dr * t;
  ci = -(di * t);
}

// -(clip(h0_diag + fake_quantize(v), -10, 10)); exact op order.
__device__ __forceinline__ float neg_a(float vv, float hd) {
  #pragma clang fp contract(off)
  float q = rintf(vv);                  // round half-even == np.rint
  q = fminf(fmaxf(q, -128.0f), 127.0f);
  float he = hd + q;
  he = fminf(fmaxf(he, -10.0f), 10.0f);
  return 0.0f - he;                     // Re(z - a)
}

// clip(+-100) -> rint -> clip(+-128); exact ops.
__device__ __forceinline__ float fq_out(float x) {
  #pragma clang fp contract(off)
  x = fminf(fmaxf(x, -100.0f), 100.0f);
  x = rintf(x);
  x = fminf(fmaxf(x, -128.0f), 127.0f);
  return x;
}

// ccf[i] = cc[i-HALO] zero-padded: i in [0, N + 2*HALO + 8)
__global__ void cc_kernel(const float* __restrict__ hsub,
                          const float* __restrict__ hsup,
                          float* __restrict__ ccf, int N) {
  #pragma clang fp contract(off)
  const int i = blockIdx.x * blockDim.x + threadIdx.x;
  if (i < N + 2*HALO + 8) {
    const int k = i - HALO;
    ccf[i] = (k >= 0 && k < N - 1) ? hsub[k] * hsup[k] : 0.0f;
  }
}

// w[0..7] = cc[m0..m0+7], where (m0+HALO) % 4 == 0: two aligned float4 loads.
__device__ __forceinline__ void load8_f(const float4* __restrict__ cc4,
                                        int m0, float* w) {
  const int q = (m0 + HALO) >> 2;
  const float4 A = cc4[q];
  const float4 B = cc4[q + 1];
  w[0]=A.x; w[1]=A.y; w[2]=A.z; w[3]=A.w;
  w[4]=B.x; w[5]=B.y; w[6]=B.z; w[7]=B.w;
}

// w[0..7] = cc[m0..m0+7], where (m0+HALO) % 4 == 3: three aligned float4 loads.
__device__ __forceinline__ void load8_b(const float4* __restrict__ cc4,
                                        int m0, float* w) {
  const int q = (m0 + HALO - 3) >> 2;   // (m0+HALO-3) % 4 == 0
  const float4 A = cc4[q];              // covers m0-3 .. m0
  const float4 B = cc4[q + 1];          // m0+1 .. m0+4
  const float4 C = cc4[q + 2];          // m0+5 .. m0+8
  w[0]=A.w;
  w[1]=B.x; w[2]=B.y; w[3]=B.z; w[4]=B.w;
  w[5]=C.x; w[6]=C.y; w[7]=C.z;
}

__global__ void __launch_bounds__(NTHR)
bk_kernel(const float* __restrict__ v,
          const float* __restrict__ hdiag,
          const float* __restrict__ ccf,      // zero-padded couplings (d_ws)
          float2* __restrict__ out,
          int N, int chunks_per_row, int blocks_per_row) {
  #pragma clang fp contract(off)
  __shared__ float sA[SPAD];            // negA for 4 chunks + halos: ~17.1 KB

  const int tid  = threadIdx.x;
  const int lane = tid & (LANES - 1);
  const int wv   = tid >> 6;
  const int row  = blockIdx.x / blocks_per_row;
  const int cb   = blockIdx.x - row * blocks_per_row;
  const int bbase = cb * BCHUNK;        // first element of the block's span
  const long rowoff = (long)row * N;
  const float4* cc4 = (const float4*)ccf;

  // ---- stage negA for all 4 chunks, 256-wide coalesced; zeros outside [0,N)
  for (int i = tid; i < BSTAGE; i += NTHR) {
    const int k = bbase - HALO + i;
    float na = 0.0f;
    if (k >= 0 && k < N) na = neg_a(v[rowoff + k], hdiag[k]);
    sA[padi(i)] = na;
  }
  __syncthreads();

  const int chunk = cb * WAVES + wv;
  if (chunk < chunks_per_row) {
    const int base = bbase + wv * CHUNK;  // this wave's chunk start
    const int s0  = base + lane * SEG;
    const int s1  = s0 + SEG;
    const int loff = bbase - HALO;        // global index of sA[0]
    const int li0 = s0 - loff;            // sA (unpadded) index of s0

    float Rr[SEG], Ri[SEG];               // R values; recycled per-8 as G
    float crB, ciB;                       // backward carry (R)
    float crF, ciF;                       // forward carry (L)
    float wcB[8], wcF[8];                 // cc windows
    float naB8[8], naF8[8];               // batched negA reads

    // ---- paired warmups (independent chains, interleaved for ILP) ---------
    // bwd: R[k-1] = cc[k-1] / (z - a[k] - R[k]), k = s1+23 .. s1, carry 0.
    // fwd: L[k+1] = cc[k]   / (z - a[k] - L[k]), k = s0-24 .. s0-1, carry 0.
    // Groups g=0,1: cheap rcp steps (pre-merge). g=2: exact Smith tail.
    // All 16 LDS reads of a group issue back-to-back before the steps.
    crB = 0.0f; ciB = 0.0f; crF = 0.0f; ciF = 0.0f;
    #pragma unroll
    for (int g = 0; g < WARM / 8; ++g) {
      const int kh = s1 + (WARM - 1) - 8 * g;   // bwd group high k
      const int kl = s0 - WARM + 8 * g;         // fwd group low k
      load8_b(cc4, kh - 8, wcB);                // wcB[j'] = cc[kh-8+j']
      load8_f(cc4, kl, wcF);                    // wcF[j]  = cc[kl+j]
      #pragma unroll
      for (int j = 0; j < 8; ++j) {
        naB8[j] = sA[padi(kh - j - loff)];
        naF8[j] = sA[padi(kl + j - loff)];
      }
      #pragma unroll
      for (int j = 0; j < 8; ++j) {
        if (g < (WCHEAP / 8)) {                 // cheap phase
          cf_cheap(naB8[j], wcB[7 - j], crB, ciB);  // cc[k-1], k = kh-j
          cf_cheap(naF8[j], wcF[j],     crF, ciF);  // cc[k],   k = kl+j
        } else {                                // exact Smith tail
          cf_step(naB8[j], wcB[7 - j], crB, ciB);
          cf_step(naF8[j], wcF[j],     crF, ciF);
        }
      }
    }
    Rr[SEG-1] = crB; Ri[SEG-1] = ciB;           // R[15]

    // ---- backward main: t = SEG-1 .. 1, store R; batched na reads ---------
    #pragma unroll
    for (int tg = 0; tg < SEG / 8; ++tg) {
      const int th = SEG - 1 - 8 * tg;          // high t of this group
      load8_b(cc4, s0 + th - 8, wcB);           // wcB[j'] = cc[s0+th-8+j']
      #pragma unroll
      for (int j = 0; j < 8; ++j)
        naB8[j] = sA[padi(li0 + th - j)];       // na at t = th-j (j=7 unused ok)
      #pragma unroll
      for (int j = 0; j < 8; ++j) {
        const int t = th - j;
        if (t >= 1) {
          cf_step(naB8[j], wcB[7 - j], crB, ciB);   // cc[k-1], k = s0+t
          Rr[t-1] = crB; Ri[t-1] = ciB;
        }
      }
    }

    // ---- forward main: two groups of 8; recycle Rr/Ri[t] as G in place,
    //      burst each group's 64 B immediately (4x dwordx4). Only 16 G
    //      values live at once -> small live set; the two half-line bursts
    //      are close enough in time that L2 write-combining holds. ---------
    float4* op = (float4*)(&out[rowoff + s0]);  // 128-B aligned
    #pragma unroll
    for (int tg = 0; tg < SEG / 8; ++tg) {
      const int kl = s0 + 8 * tg;
      load8_f(cc4, kl, wcF);                    // wcF[j] = cc[kl+j]
      #pragma unroll
      for (int j = 0; j < 8; ++j)
        naF8[j] = sA[padi(li0 + 8 * tg + j)];
      #pragma unroll
      for (int j = 0; j < 8; ++j) {
        const int t = 8 * tg + j;
        const float drL = naF8[j] - crF;        // (z - a) - L
        const float diL = 1.0f - ciF;
        const float drf = drL - Rr[t];          // ... - R
        const float dif = diL - Ri[t];
        const C2 G = npdiv(1.0f, drf, dif);
        Rr[t] = fq_out(G.r);                    // recycle R slot as G out
        Ri[t] = fq_out(G.i);
        if (t < SEG - 1) {                      // advance L within segment
          const C2 nc = npdiv(wcF[j], drL, diL);
          crF = nc.r; ciF = nc.i;
        }
      }
      #pragma unroll
      for (int q = 0; q < 4; ++q) {             // burst this group's 64 B
        float4 f4;
        f4.x = Rr[8*tg + 2*q];     f4.y = Ri[8*tg + 2*q];
        f4.z = Rr[8*tg + 2*q + 1]; f4.w = Ri[8*tg + 2*q + 1];
        op[4*tg + q] = f4;
      }
    }
  }
}

extern "C" void kernel_launch(void* const* d_in, const int* in_sizes, int n_in,
                              void* d_out, int out_size, void* d_ws, size_t ws_size,
                              hipStream_t stream) {
  const float* v    = (const float*)d_in[0];
  const float* hd   = (const float*)d_in[1];
  const float* hsub = (const float*)d_in[2];
  const float* hsup = (const float*)d_in[3];
  const int N = in_sizes[1];
  const int B = in_sizes[0] / N;
  const int chunks = (N + CHUNK - 1) / CHUNK;        // 16 for N=16384 (exact)
  const int bpr    = (chunks + WAVES - 1) / WAVES;   // 4 blocks per row

  float* ccf = (float*)d_ws;                     // N + 2*HALO + 8 floats
  const int ccn = N + 2*HALO + 8;
  cc_kernel<<<(ccn + 255) / 256, 256, 0, stream>>>(hsub, hsup, ccf, N);
  bk_kernel<<<B * bpr, NTHR, 0, stream>>>(v, hd, ccf, (float2*)d_out,
                                          N, chunks, bpr);
}